// Round 1
// baseline (234.144 us; speedup 1.0000x reference)
//
#include <hip/hip_runtime.h>
#include <hip/hip_bf16.h>

#define BB 4
#define SS 2048
#define DM 1024
#define DN 64

typedef short short8 __attribute__((ext_vector_type(8)));
typedef float f32x4 __attribute__((ext_vector_type(4)));
typedef unsigned short ushort;

__device__ __forceinline__ ushort f2bf(float f) {
    union { float f; unsigned u; } v; v.f = f;
    unsigned r = v.u + 0x7fffu + ((v.u >> 16) & 1u);
    return (ushort)(r >> 16);
}

// ---------------------------------------------------------------------------
// prep_w: convert w_q|w_k|w_v (each [64][1024] fp32) to bf16, same layout.
// ---------------------------------------------------------------------------
__global__ __launch_bounds__(256) void prep_w(
    const float* __restrict__ wq, const float* __restrict__ wk,
    const float* __restrict__ wv, ushort* __restrict__ w_bf)
{
    int i = blockIdx.x * 256 + threadIdx.x;          // 49152 threads, 4 floats each
    int p = i >> 14;                                  // 16384 float4 per proj
    int j = (i & 16383) * 4;
    const float* src = (p == 0) ? wq : (p == 1) ? wk : wv;
    float4 f = *(const float4*)(src + j);
    ushort o[4] = { f2bf(f.x), f2bf(f.y), f2bf(f.z), f2bf(f.w) };
    *(unsigned long long*)(w_bf + p * 65536 + j) = *(unsigned long long*)o;
}

// ---------------------------------------------------------------------------
// proj: out = x @ w^T + b.
// K-split x4 within a block: 4 waves share one 16-row group; wave w covers
// K in [256w, 256w+256). Was 1536 waves total (18.75% occupancy hard cap,
// latency-bound at 14% occ / 1.1 TB/s); now 6144 waves (75% cap). Partial
// sums reduced through 16 KB LDS (stride 65 to spread banks), bias + bf16
// pack + store fused into the reduce phase. A-frags direct from global fp32,
// B-frags direct from bf16 w (L2-hot, 128 KB/proj).
// qp/kp row-major bf16 [8192][64]; vp transposed [4][64][2048].
// ---------------------------------------------------------------------------
__global__ __launch_bounds__(256, 6) void proj_kernel(
    const float* __restrict__ q, const float* __restrict__ k, const float* __restrict__ v,
    const ushort* __restrict__ w_bf,
    const float* __restrict__ bq, const float* __restrict__ bk, const float* __restrict__ bvp,
    ushort* __restrict__ qp, ushort* __restrict__ kp, ushort* __restrict__ vpT)
{
    __shared__ __align__(16) float red[4][16][65];   // 16640 B, +65 stride spreads banks

    const int tid  = threadIdx.x;
    const int wv_id = tid >> 6;                      // 0..3 = K-quarter
    const int lane  = tid & 63;
    const int l16   = lane & 15;
    const int quad  = lane >> 4;
    const int proj  = blockIdx.y;
    const int m0    = blockIdx.x * 16;               // 512 row-groups per proj

    const float* x     = (proj == 0) ? q  : (proj == 1) ? k  : v;
    const ushort* wb   = w_bf + proj * 65536;

    const float* arow = x + (size_t)(m0 + l16) * DM + quad * 8;
    const int kb0 = wv_id << 8;                      // 256-wide K slice per wave

    f32x4 acc[4];
#pragma unroll
    for (int t = 0; t < 4; t++) acc[t] = (f32x4){0.f, 0.f, 0.f, 0.f};

#pragma unroll 2
    for (int kb = kb0; kb < kb0 + 256; kb += 32) {
        float4 f0 = *(const float4*)(arow + kb);
        float4 f1 = *(const float4*)(arow + kb + 4);
        ushort ta[8] = { f2bf(f0.x), f2bf(f0.y), f2bf(f0.z), f2bf(f0.w),
                         f2bf(f1.x), f2bf(f1.y), f2bf(f1.z), f2bf(f1.w) };
        short8 a = *(short8*)ta;
#pragma unroll
        for (int t = 0; t < 4; t++) {
            short8 b = *(const short8*)(wb + (size_t)(t * 16 + l16) * DM + kb + quad * 8);
            acc[t] = __builtin_amdgcn_mfma_f32_16x16x32_bf16(a, b, acc[t], 0, 0, 0);
        }
    }

    // C/D layout: n = t*16 + l16, row = quad*4 + r. Park partials in LDS.
#pragma unroll
    for (int t = 0; t < 4; t++)
#pragma unroll
        for (int r = 0; r < 4; r++)
            red[wv_id][quad * 4 + r][t * 16 + l16] = acc[t][r];
    __syncthreads();

    // Reduce 4 K-slices; each wave finalizes 4 rows (col = lane, coalesced).
    const float* bias = (proj == 0) ? bq : (proj == 1) ? bk : bvp;
    const int col   = tid & 63;
    const int rbase = tid >> 6;
    const float bb_ = bias[col];
#pragma unroll
    for (int rr = 0; rr < 4; rr++) {
        const int row = rr * 4 + rbase;
        float s_ = red[0][row][col] + red[1][row][col]
                 + red[2][row][col] + red[3][row][col];
        ushort h = f2bf(s_ + bb_);
        int grow = m0 + row;
        if (proj == 0)      qp[(size_t)grow * DN + col] = h;
        else if (proj == 1) kp[(size_t)grow * DN + col] = h;
        else {
            int bb = grow >> 11, s = grow & 2047;
            vpT[((size_t)bb * DN + col) * SS + s] = h;
        }
    }
}

// ---------------------------------------------------------------------------
// flash: barrier-free. One wave = 16 q rows x one key-slice. All MFMA frags
// loaded directly from global (bf16, 16B/lane). P roundtrip via wave-private
// LDS. Mask applied in fp32. Writes unnormalized partial (O, m, l).
// ---------------------------------------------------------------------------
__global__ __launch_bounds__(256, 4) void flash_kernel(
    const float* __restrict__ mask,
    const ushort* __restrict__ qp,
    const ushort* __restrict__ kp,
    const ushort* __restrict__ vpT,
    float* __restrict__ part_O,     // [split][8192][64]
    float* __restrict__ part_ml,    // [split][8192][2]
    int nslice, int keys_per_slice)
{
    __shared__ __align__(16) ushort p_lds[4][16][80];  // 160B row stride: quads spread 8 banks

    const int tid  = threadIdx.x;
    const int wv   = tid >> 6;
    const int lane = tid & 63;
    const int l16  = lane & 15;
    const int quad = lane >> 4;

    const int gw     = blockIdx.x * 4 + wv;       // global wave id
    const int qg     = gw & 127;                  // q-group within batch (128/batch)
    const int rest   = gw >> 7;
    const int slice  = rest % nslice;
    const int b      = rest / nslice;

    // Q fragments (A-layout), direct from global
    const ushort* qbase = qp + ((size_t)b * SS + qg * 16 + l16) * DN + quad * 8;
    short8 aq0 = *(const short8*)(qbase);
    short8 aq1 = *(const short8*)(qbase + 32);

    float m_r[4] = { -__builtin_inff(), -__builtin_inff(),
                     -__builtin_inff(), -__builtin_inff() };
    float l_r[4] = { 0.f, 0.f, 0.f, 0.f };
    f32x4 Oacc[4];
#pragma unroll
    for (int t = 0; t < 4; t++) Oacc[t] = (f32x4){0.f, 0.f, 0.f, 0.f};

    const size_t mrow0 = ((size_t)b * SS + qg * 16 + quad * 4) * SS;
    const int k_begin = slice * keys_per_slice;
    const int k_end   = k_begin + keys_per_slice;

    for (int k0 = k_begin; k0 < k_end; k0 += 64) {
        // fp32 mask loads (argmax decided by ~1e2 score gaps -> must stay fp32)
        float mk[4][4];
#pragma unroll
        for (int t = 0; t < 4; t++)
#pragma unroll
            for (int r = 0; r < 4; r++)
                mk[t][r] = mask[mrow0 + (size_t)r * SS + k0 + t * 16 + l16];

        // S = qp . kp^T ; B-frags direct from global kp (row-major)
        f32x4 sc[4];
#pragma unroll
        for (int t = 0; t < 4; t++) {
            const ushort* kb_ = kp + ((size_t)b * SS + k0 + t * 16 + l16) * DN + quad * 8;
            short8 bk0 = *(const short8*)(kb_);
            short8 bk1 = *(const short8*)(kb_ + 32);
            f32x4 z = (f32x4){0.f, 0.f, 0.f, 0.f};
            z = __builtin_amdgcn_mfma_f32_16x16x32_bf16(aq0, bk0, z, 0, 0, 0);
            z = __builtin_amdgcn_mfma_f32_16x16x32_bf16(aq1, bk1, z, 0, 0, 0);
            sc[t] = z;
        }

        // online softmax per accumulator reg (one q row per reg)
#pragma unroll
        for (int r = 0; r < 4; r++) {
            float s[4];
            float tmax = -__builtin_inff();
#pragma unroll
            for (int t = 0; t < 4; t++) {
                s[t] = sc[t][r] * 0.125f - 1e9f * mk[t][r];
                tmax = fmaxf(tmax, s[t]);
            }
#pragma unroll
            for (int off = 8; off >= 1; off >>= 1)
                tmax = fmaxf(tmax, __shfl_xor(tmax, off, 16));
            float mnew  = fmaxf(m_r[r], tmax);
            float alpha = __expf(m_r[r] - mnew);
            m_r[r] = mnew;
            float rs = 0.f;
#pragma unroll
            for (int t = 0; t < 4; t++) {
                float pv = __expf(s[t] - mnew);
                rs += pv;
                p_lds[wv][quad * 4 + r][t * 16 + l16] = f2bf(pv);
            }
#pragma unroll
            for (int off = 8; off >= 1; off >>= 1)
                rs += __shfl_xor(rs, off, 16);
            l_r[r] = l_r[r] * alpha + rs;
#pragma unroll
            for (int tf = 0; tf < 4; tf++)
                Oacc[tf][r] *= alpha;
        }
        // wave-private LDS roundtrip: in-order DS pipe, no barrier needed

        short8 ap0 = *(const short8*)&p_lds[wv][l16][quad * 8];
        short8 ap1 = *(const short8*)&p_lds[wv][l16][32 + quad * 8];
#pragma unroll
        for (int tf = 0; tf < 4; tf++) {
            const ushort* vb_ = vpT + ((size_t)b * DN + tf * 16 + l16) * SS + k0 + quad * 8;
            short8 bv0 = *(const short8*)(vb_);
            short8 bv1 = *(const short8*)(vb_ + 32);
            Oacc[tf] = __builtin_amdgcn_mfma_f32_16x16x32_bf16(ap0, bv0, Oacc[tf], 0, 0, 0);
            Oacc[tf] = __builtin_amdgcn_mfma_f32_16x16x32_bf16(ap1, bv1, Oacc[tf], 0, 0, 0);
        }
    }

    // store partials (unnormalized O, plus m and l)
    const int rowg = (b * SS + qg * 16) + quad * 4;   // global row base for this quad
#pragma unroll
    for (int r = 0; r < 4; r++) {
        size_t row = (size_t)rowg + r;
        if (l16 == 0) {
            part_ml[((size_t)slice * (BB * SS) + row) * 2 + 0] = m_r[r];
            part_ml[((size_t)slice * (BB * SS) + row) * 2 + 1] = l_r[r];
        }
#pragma unroll
        for (int tf = 0; tf < 4; tf++)
            part_O[((size_t)slice * (BB * SS) + row) * DN + tf * 16 + l16] = Oacc[tf][r];
    }
}

// ---------------------------------------------------------------------------
// combine: merge nslice partials per row; normalize.
// ---------------------------------------------------------------------------
__global__ __launch_bounds__(256) void combine_kernel(
    const float* __restrict__ part_O, const float* __restrict__ part_ml,
    float* __restrict__ out, int nslice)
{
    const int tid = threadIdx.x;
    const int row = blockIdx.x * 4 + (tid >> 6);
    const int f   = tid & 63;

    float ms[8], ls[8];
    float M = -__builtin_inff();
    for (int i = 0; i < nslice; i++) {
        ms[i] = part_ml[((size_t)i * (BB * SS) + row) * 2 + 0];
        ls[i] = part_ml[((size_t)i * (BB * SS) + row) * 2 + 1];
        M = fmaxf(M, ms[i]);
    }
    float L = 0.f, acc = 0.f;
    for (int i = 0; i < nslice; i++) {
        float e = __expf(ms[i] - M);
        L += e * ls[i];
        acc += e * part_O[((size_t)i * (BB * SS) + row) * DN + f];
    }
    out[(size_t)row * DN + f] = acc / L;
}

extern "C" void kernel_launch(void* const* d_in, const int* in_sizes, int n_in,
                              void* d_out, int out_size, void* d_ws, size_t ws_size,
                              hipStream_t stream) {
    const float* q    = (const float*)d_in[0];
    const float* k    = (const float*)d_in[1];
    const float* v    = (const float*)d_in[2];
    const float* mask = (const float*)d_in[3];
    const float* wq   = (const float*)d_in[4];
    const float* bq   = (const float*)d_in[5];
    const float* wk   = (const float*)d_in[6];
    const float* bk   = (const float*)d_in[7];
    const float* wv   = (const float*)d_in[8];
    const float* bv   = (const float*)d_in[9];
    float* out = (float*)d_out;

    // workspace layout
    char* p = (char*)d_ws;
    ushort* w_bf = (ushort*)p;                 p += 3 * 65536 * sizeof(ushort);   // 384 KB
    ushort* qp   = (ushort*)p;                 p += (size_t)BB * SS * DN * 2;     // 1 MB
    ushort* kp   = (ushort*)p;                 p += (size_t)BB * SS * DN * 2;     // 1 MB
    ushort* vpT  = (ushort*)p;                 p += (size_t)BB * SS * DN * 2;     // 1 MB
    size_t fixed = (size_t)(p - (char*)d_ws);

    int split = 8;
    while (split > 1 &&
           fixed + (size_t)split * ((size_t)BB * SS * 2 * 4 + (size_t)BB * SS * DN * 4) > ws_size)
        split >>= 1;

    float* part_ml = (float*)p;                p += (size_t)split * BB * SS * 2 * 4;
    float* part_O  = (float*)p;

    int keys_per_slice = SS / split;

    prep_w<<<192, 256, 0, stream>>>(wq, wk, wv, w_bf);
    proj_kernel<<<dim3(512, 3), 256, 0, stream>>>(q, k, v, w_bf, bq, bk, bv, qp, kp, vpT);
    flash_kernel<<<128 * split, 256, 0, stream>>>(mask, qp, kp, vpT, part_O, part_ml,
                                                  split, keys_per_slice);
    combine_kernel<<<(BB * SS) / 4, 256, 0, stream>>>(part_O, part_ml, out, split);
}

// Round 2
// 231.964 us; speedup vs baseline: 1.0094x; 1.0094x over previous
//
#include <hip/hip_runtime.h>
#include <hip/hip_bf16.h>

#define BB 4
#define SS 2048
#define DM 1024
#define DN 64

typedef short short8 __attribute__((ext_vector_type(8)));
typedef float f32x4 __attribute__((ext_vector_type(4)));
typedef unsigned short ushort;

__device__ __forceinline__ ushort f2bf(float f) {
    union { float f; unsigned u; } v; v.f = f;
    unsigned r = v.u + 0x7fffu + ((v.u >> 16) & 1u);
    return (ushort)(r >> 16);
}

// ---------------------------------------------------------------------------
// prep_w: convert w_q|w_k|w_v (each [64][1024] fp32) to bf16, same layout.
// ---------------------------------------------------------------------------
__global__ __launch_bounds__(256) void prep_w(
    const float* __restrict__ wq, const float* __restrict__ wk,
    const float* __restrict__ wv, ushort* __restrict__ w_bf)
{
    int i = blockIdx.x * 256 + threadIdx.x;          // 49152 threads, 4 floats each
    int p = i >> 14;                                  // 16384 float4 per proj
    int j = (i & 16383) * 4;
    const float* src = (p == 0) ? wq : (p == 1) ? wk : wv;
    float4 f = *(const float4*)(src + j);
    ushort o[4] = { f2bf(f.x), f2bf(f.y), f2bf(f.z), f2bf(f.w) };
    *(unsigned long long*)(w_bf + p * 65536 + j) = *(unsigned long long*)o;
}

// ---------------------------------------------------------------------------
// proj: out = x @ w^T + b.
// Round-1 lesson: occupancy 14->53% did NOT help (dur 50.8->56.3 us). Both
// rounds pinned at ~1 TB/s HBM with all pipes idle -> transaction-pattern
// bound: direct-from-global MFMA frags touch 16 scattered 128B chunks at
// 4KB stride per wave-instr (~32 cacheline transactions each).
// Fix: coalesced cooperative staging of A through LDS. Block = 2 waves,
// 32 rows, four 256-wide K-chunks, double-buffered. Staging loads are
// 1KB-contiguous per wave-instr, 16 float4/thread in flight (MLP), fp32->
// bf16 on stage, A-frags via ds_read_b128 (row stride 264 bf16: conflict-
// free). T14 split: issue chunk c+1 loads BEFORE computing chunk c.
// B (w, 128KB/proj) stays direct-from-global: same addresses across waves/
// blocks on a CU -> L1-hot. No K-split -> no reduce, no extra barriers.
// qp/kp row-major bf16 [8192][64]; vp transposed [4][64][2048].
// ---------------------------------------------------------------------------
__global__ __launch_bounds__(128) void proj_kernel(
    const float* __restrict__ q, const float* __restrict__ k, const float* __restrict__ v,
    const ushort* __restrict__ w_bf,
    const float* __restrict__ bq, const float* __restrict__ bk, const float* __restrict__ bvp,
    ushort* __restrict__ qp, ushort* __restrict__ kp, ushort* __restrict__ vpT)
{
    __shared__ __align__(16) ushort sA[2][32][264];   // 33 KB, +8 pad per row

    const int tid  = threadIdx.x;
    const int wv_id = tid >> 6;                       // 0..1
    const int lane  = tid & 63;
    const int l16   = lane & 15;
    const int quad  = lane >> 4;
    const int proj  = blockIdx.y;
    const int m0    = blockIdx.x * 32;                // 256 row-groups per proj

    const float* x   = (proj == 0) ? q  : (proj == 1) ? k  : v;
    const ushort* wb = w_bf + proj * 65536;

    f32x4 acc[4];
#pragma unroll
    for (int t = 0; t < 4; t++) acc[t] = (f32x4){0.f, 0.f, 0.f, 0.f};

    float4 st[16];

    // prologue: stage chunk 0 (rows: 2*it + wv_id, cols: lane*4 -> coalesced 1KB/wave-instr)
#pragma unroll
    for (int it = 0; it < 16; it++)
        st[it] = *(const float4*)(x + (size_t)(m0 + 2 * it + wv_id) * DM + lane * 4);
#pragma unroll
    for (int it = 0; it < 16; it++) {
        ushort o[4] = { f2bf(st[it].x), f2bf(st[it].y), f2bf(st[it].z), f2bf(st[it].w) };
        *(unsigned long long*)&sA[0][2 * it + wv_id][lane * 4] = *(unsigned long long*)o;
    }
    __syncthreads();

#pragma unroll
    for (int c = 0; c < 4; c++) {
        const int cur = c & 1;
        // T14: issue next chunk's global loads before compute
        if (c < 3) {
#pragma unroll
            for (int it = 0; it < 16; it++)
                st[it] = *(const float4*)(x + (size_t)(m0 + 2 * it + wv_id) * DM
                                            + (c + 1) * 256 + lane * 4);
        }
        // compute chunk c: wave owns rows [wv_id*16, wv_id*16+16)
#pragma unroll
        for (int s = 0; s < 8; s++) {
            const int kbL = s * 32;
            short8 a = *(const short8*)&sA[cur][wv_id * 16 + l16][kbL + quad * 8];
#pragma unroll
            for (int t = 0; t < 4; t++) {
                short8 b = *(const short8*)(wb + (size_t)(t * 16 + l16) * DM
                                               + c * 256 + kbL + quad * 8);
                acc[t] = __builtin_amdgcn_mfma_f32_16x16x32_bf16(a, b, acc[t], 0, 0, 0);
            }
        }
        // write next chunk into the other buffer
        if (c < 3) {
#pragma unroll
            for (int it = 0; it < 16; it++) {
                ushort o[4] = { f2bf(st[it].x), f2bf(st[it].y), f2bf(st[it].z), f2bf(st[it].w) };
                *(unsigned long long*)&sA[cur ^ 1][2 * it + wv_id][lane * 4] =
                    *(unsigned long long*)o;
            }
        }
        __syncthreads();
    }

    // epilogue: C/D layout: n = t*16 + l16, row = quad*4 + r
    const float* bias = (proj == 0) ? bq : (proj == 1) ? bk : bvp;
#pragma unroll
    for (int t = 0; t < 4; t++) {
        int n = t * 16 + l16;
        float bb_ = bias[n];
#pragma unroll
        for (int r = 0; r < 4; r++) {
            int grow = m0 + wv_id * 16 + quad * 4 + r;
            ushort h = f2bf(acc[t][r] + bb_);
            if (proj == 0)      qp[(size_t)grow * DN + n] = h;
            else if (proj == 1) kp[(size_t)grow * DN + n] = h;
            else {
                int bb = grow >> 11, s = grow & 2047;
                vpT[((size_t)bb * DN + n) * SS + s] = h;
            }
        }
    }
}

// ---------------------------------------------------------------------------
// flash: barrier-free. One wave = 16 q rows x one key-slice. All MFMA frags
// loaded directly from global (bf16, 16B/lane). P roundtrip via wave-private
// LDS. Mask applied in fp32. Writes unnormalized partial (O, m, l).
// ---------------------------------------------------------------------------
__global__ __launch_bounds__(256, 4) void flash_kernel(
    const float* __restrict__ mask,
    const ushort* __restrict__ qp,
    const ushort* __restrict__ kp,
    const ushort* __restrict__ vpT,
    float* __restrict__ part_O,     // [split][8192][64]
    float* __restrict__ part_ml,    // [split][8192][2]
    int nslice, int keys_per_slice)
{
    __shared__ __align__(16) ushort p_lds[4][16][80];  // 160B row stride: quads spread 8 banks

    const int tid  = threadIdx.x;
    const int wv   = tid >> 6;
    const int lane = tid & 63;
    const int l16  = lane & 15;
    const int quad = lane >> 4;

    const int gw     = blockIdx.x * 4 + wv;       // global wave id
    const int qg     = gw & 127;                  // q-group within batch (128/batch)
    const int rest   = gw >> 7;
    const int slice  = rest % nslice;
    const int b      = rest / nslice;

    // Q fragments (A-layout), direct from global
    const ushort* qbase = qp + ((size_t)b * SS + qg * 16 + l16) * DN + quad * 8;
    short8 aq0 = *(const short8*)(qbase);
    short8 aq1 = *(const short8*)(qbase + 32);

    float m_r[4] = { -__builtin_inff(), -__builtin_inff(),
                     -__builtin_inff(), -__builtin_inff() };
    float l_r[4] = { 0.f, 0.f, 0.f, 0.f };
    f32x4 Oacc[4];
#pragma unroll
    for (int t = 0; t < 4; t++) Oacc[t] = (f32x4){0.f, 0.f, 0.f, 0.f};

    const size_t mrow0 = ((size_t)b * SS + qg * 16 + quad * 4) * SS;
    const int k_begin = slice * keys_per_slice;
    const int k_end   = k_begin + keys_per_slice;

    for (int k0 = k_begin; k0 < k_end; k0 += 64) {
        // fp32 mask loads (argmax decided by ~1e2 score gaps -> must stay fp32)
        float mk[4][4];
#pragma unroll
        for (int t = 0; t < 4; t++)
#pragma unroll
            for (int r = 0; r < 4; r++)
                mk[t][r] = mask[mrow0 + (size_t)r * SS + k0 + t * 16 + l16];

        // S = qp . kp^T ; B-frags direct from global kp (row-major)
        f32x4 sc[4];
#pragma unroll
        for (int t = 0; t < 4; t++) {
            const ushort* kb_ = kp + ((size_t)b * SS + k0 + t * 16 + l16) * DN + quad * 8;
            short8 bk0 = *(const short8*)(kb_);
            short8 bk1 = *(const short8*)(kb_ + 32);
            f32x4 z = (f32x4){0.f, 0.f, 0.f, 0.f};
            z = __builtin_amdgcn_mfma_f32_16x16x32_bf16(aq0, bk0, z, 0, 0, 0);
            z = __builtin_amdgcn_mfma_f32_16x16x32_bf16(aq1, bk1, z, 0, 0, 0);
            sc[t] = z;
        }

        // online softmax per accumulator reg (one q row per reg)
#pragma unroll
        for (int r = 0; r < 4; r++) {
            float s[4];
            float tmax = -__builtin_inff();
#pragma unroll
            for (int t = 0; t < 4; t++) {
                s[t] = sc[t][r] * 0.125f - 1e9f * mk[t][r];
                tmax = fmaxf(tmax, s[t]);
            }
#pragma unroll
            for (int off = 8; off >= 1; off >>= 1)
                tmax = fmaxf(tmax, __shfl_xor(tmax, off, 16));
            float mnew  = fmaxf(m_r[r], tmax);
            float alpha = __expf(m_r[r] - mnew);
            m_r[r] = mnew;
            float rs = 0.f;
#pragma unroll
            for (int t = 0; t < 4; t++) {
                float pv = __expf(s[t] - mnew);
                rs += pv;
                p_lds[wv][quad * 4 + r][t * 16 + l16] = f2bf(pv);
            }
#pragma unroll
            for (int off = 8; off >= 1; off >>= 1)
                rs += __shfl_xor(rs, off, 16);
            l_r[r] = l_r[r] * alpha + rs;
#pragma unroll
            for (int tf = 0; tf < 4; tf++)
                Oacc[tf][r] *= alpha;
        }
        // wave-private LDS roundtrip: in-order DS pipe, no barrier needed

        short8 ap0 = *(const short8*)&p_lds[wv][l16][quad * 8];
        short8 ap1 = *(const short8*)&p_lds[wv][l16][32 + quad * 8];
#pragma unroll
        for (int tf = 0; tf < 4; tf++) {
            const ushort* vb_ = vpT + ((size_t)b * DN + tf * 16 + l16) * SS + k0 + quad * 8;
            short8 bv0 = *(const short8*)(vb_);
            short8 bv1 = *(const short8*)(vb_ + 32);
            Oacc[tf] = __builtin_amdgcn_mfma_f32_16x16x32_bf16(ap0, bv0, Oacc[tf], 0, 0, 0);
            Oacc[tf] = __builtin_amdgcn_mfma_f32_16x16x32_bf16(ap1, bv1, Oacc[tf], 0, 0, 0);
        }
    }

    // store partials (unnormalized O, plus m and l)
    const int rowg = (b * SS + qg * 16) + quad * 4;   // global row base for this quad
#pragma unroll
    for (int r = 0; r < 4; r++) {
        size_t row = (size_t)rowg + r;
        if (l16 == 0) {
            part_ml[((size_t)slice * (BB * SS) + row) * 2 + 0] = m_r[r];
            part_ml[((size_t)slice * (BB * SS) + row) * 2 + 1] = l_r[r];
        }
#pragma unroll
        for (int tf = 0; tf < 4; tf++)
            part_O[((size_t)slice * (BB * SS) + row) * DN + tf * 16 + l16] = Oacc[tf][r];
    }
}

// ---------------------------------------------------------------------------
// combine: merge nslice partials per row; normalize.
// ---------------------------------------------------------------------------
__global__ __launch_bounds__(256) void combine_kernel(
    const float* __restrict__ part_O, const float* __restrict__ part_ml,
    float* __restrict__ out, int nslice)
{
    const int tid = threadIdx.x;
    const int row = blockIdx.x * 4 + (tid >> 6);
    const int f   = tid & 63;

    float ms[8], ls[8];
    float M = -__builtin_inff();
    for (int i = 0; i < nslice; i++) {
        ms[i] = part_ml[((size_t)i * (BB * SS) + row) * 2 + 0];
        ls[i] = part_ml[((size_t)i * (BB * SS) + row) * 2 + 1];
        M = fmaxf(M, ms[i]);
    }
    float L = 0.f, acc = 0.f;
    for (int i = 0; i < nslice; i++) {
        float e = __expf(ms[i] - M);
        L += e * ls[i];
        acc += e * part_O[((size_t)i * (BB * SS) + row) * DN + f];
    }
    out[(size_t)row * DN + f] = acc / L;
}

extern "C" void kernel_launch(void* const* d_in, const int* in_sizes, int n_in,
                              void* d_out, int out_size, void* d_ws, size_t ws_size,
                              hipStream_t stream) {
    const float* q    = (const float*)d_in[0];
    const float* k    = (const float*)d_in[1];
    const float* v    = (const float*)d_in[2];
    const float* mask = (const float*)d_in[3];
    const float* wq   = (const float*)d_in[4];
    const float* bq   = (const float*)d_in[5];
    const float* wk   = (const float*)d_in[6];
    const float* bk   = (const float*)d_in[7];
    const float* wv   = (const float*)d_in[8];
    const float* bv   = (const float*)d_in[9];
    float* out = (float*)d_out;

    // workspace layout
    char* p = (char*)d_ws;
    ushort* w_bf = (ushort*)p;                 p += 3 * 65536 * sizeof(ushort);   // 384 KB
    ushort* qp   = (ushort*)p;                 p += (size_t)BB * SS * DN * 2;     // 1 MB
    ushort* kp   = (ushort*)p;                 p += (size_t)BB * SS * DN * 2;     // 1 MB
    ushort* vpT  = (ushort*)p;                 p += (size_t)BB * SS * DN * 2;     // 1 MB
    size_t fixed = (size_t)(p - (char*)d_ws);

    int split = 8;
    while (split > 1 &&
           fixed + (size_t)split * ((size_t)BB * SS * 2 * 4 + (size_t)BB * SS * DN * 4) > ws_size)
        split >>= 1;

    float* part_ml = (float*)p;                p += (size_t)split * BB * SS * 2 * 4;
    float* part_O  = (float*)p;

    int keys_per_slice = SS / split;

    prep_w<<<192, 256, 0, stream>>>(wq, wk, wv, w_bf);
    proj_kernel<<<dim3(256, 3), 128, 0, stream>>>(q, k, v, w_bf, bq, bk, bv, qp, kp, vpT);
    flash_kernel<<<128 * split, 256, 0, stream>>>(mask, qp, kp, vpT, part_O, part_ml,
                                                  split, keys_per_slice);
    combine_kernel<<<(BB * SS) / 4, 256, 0, stream>>>(part_O, part_ml, out, split);
}